// Round 4
// baseline (950.198 us; speedup 1.0000x reference)
//
#include <hip/hip_runtime.h>
#include <hip/hip_cooperative_groups.h>

// MinimalSSM via MFMA, scan-free: Bu = U@B^T (bf16 MFMA), then
// H[t,s] = a_s^t * ( cumsum_{tau<=t} a_s^{-tau} Bu[tau,s] + a_s*c0_s )
// (cumsum = triangular ones-GEMM on MFMA). Y = H@C^T + U@D^T.
// R9: single-pass fusion made DEADLOCK-FREE. R8's decoupled-lookback spin
// hung (dispatch-order-dependent wait with grid > resident capacity, vs
// G16). Now: cooperative persistent blocks (grid = occupancy-derived
// co-resident count, ~768), each handles ceil(2048/grid) chunks in rounds.
// Per round: GEMM1 -> publish agg[g] -> grid.sync() -> lookback (<=48
// predecessors, all published; a^(48L) <= 3e-20 so truncation exact) ->
// tri-GEMM -> GEMM2 -> Y. No spin, no flags; visibility via threadfence +
// grid.sync device-scope fences. K1 (dup U read + GEMM1, ~85us) and K2
// deleted. (R7 verdict: WRITE_SIZE 2.125x is a counter artifact.)

#define TT   262144
#define DIN  64
#define DS   128
#define DTC  0.01f
#define L    128
#define NG   (TT / L)        // 2048 chunks
#define LBD  48              // lookback depth (a^(L*48) < 1e-19 worst-case)

typedef short  s8v  __attribute__((ext_vector_type(8)));
typedef short  s4v  __attribute__((ext_vector_type(4)));
typedef float  f4v  __attribute__((ext_vector_type(4)));

__device__ __forceinline__ unsigned short f2bf(float f) {
    unsigned u = __float_as_uint(f);
    u += 0x7fffu + ((u >> 16) & 1u);        // round-to-nearest-even
    return (unsigned short)(u >> 16);
}

__device__ __forceinline__ s8v pack8(float4 a, float4 b) {
    union { unsigned short u[8]; s8v v; } r;
    r.u[0] = f2bf(a.x); r.u[1] = f2bf(a.y); r.u[2] = f2bf(a.z); r.u[3] = f2bf(a.w);
    r.u[4] = f2bf(b.x); r.u[5] = f2bf(b.y); r.u[6] = f2bf(b.z); r.u[7] = f2bf(b.w);
    return r.v;
}

__device__ __forceinline__ s4v pack4(float x, float y, float z, float w) {
    union { unsigned short u[4]; s4v v; } r;
    r.u[0] = f2bf(x); r.u[1] = f2bf(y); r.u[2] = f2bf(z); r.u[3] = f2bf(w);
    return r.v;
}

// Fragment-granule LDS layout for bf16 matrix X[row][col], 8-col granules:
// ushort index = ((rtile*NCO + co)*16 + (mf ^ (co&15))) * 8.
__device__ __forceinline__ int gidx(int NCO, int rtile, int co, int mf) {
    return (((rtile * NCO + co) << 4) + (mf ^ (co & 15))) << 3;
}

__device__ __forceinline__ s8v ldfrag(const unsigned short* S, int NCO,
                                      int rtile, int kt, int q, int m) {
    return *(const s8v*)&S[gidx(NCO, rtile, kt * 4 + q, m)];
}

// Stage U chunk (128 x 64 fp32) -> bf16 A-frag granules.
__device__ __forceinline__ void stage_U(const float* __restrict__ Ug,
                                        unsigned short* __restrict__ sA,
                                        int tid) {
    #pragma unroll
    for (int p = 0; p < 2; ++p) {
        int u  = tid + p * 512;
        int co = u & 7, m = (u >> 3) & 15, mt = u >> 7;
        const float4* gp = (const float4*)(Ug + (mt * 16 + m) * DIN + co * 8);
        *(s8v*)&sA[gidx(8, mt, co, m)] = pack8(gp[0], gp[1]);
    }
}

__device__ __forceinline__ s8v load_bfrag(const float* __restrict__ M,
                                          int row, int k0, int ld) {
    const float4* p = (const float4*)(M + row * ld + k0);
    return pack8(p[0], p[1]);
}

// ---------------------------------------------------------------- fused
__global__ __launch_bounds__(512, 6) void ssm_fused(
    const float* __restrict__ U, const float* __restrict__ Alog,
    const float* __restrict__ B, const float* __restrict__ C,
    const float* __restrict__ Dm, const float* __restrict__ h0,
    float* __restrict__ agg, float* __restrict__ Y, float* __restrict__ hfin)
{
    __shared__ __align__(16) unsigned char smem[49152];      // 48 KB
    unsigned short* sA = (unsigned short*)smem;              // 16 KB U frags
    unsigned short* sT = (unsigned short*)(smem + 16384);    // 32 KB Bu'^T / H^T
    float*          sY = (float*)smem;                       // overlay, 128x68 f32
    __shared__ float sCA[DS];
    __shared__ float sDc[DS];

    const int tid  = threadIdx.x;
    const int lane = tid & 63;
    const int w    = tid >> 6;
    const int q    = lane >> 4, m = lane & 15;
    const int mi   = w & 3, th = w >> 2;

    // ---- per-thread constants, hoisted across rounds
    s8v Bf[2];
    #pragma unroll
    for (int ks = 0; ks < 2; ++ks)
        Bf[ks] = load_bfrag(B, 16 * w + m, ks * 32 + q * 8, DIN);
    const float cA   = Alog[16 * w + m] * DTC;
    const float ainv = __expf(-cA);
    const float a16i = __expf(-16.f * cA);
    const float fmt0 = __expf(-cA * (float)(4 * q));
    const float aPub = __expf(cA * 127.f);
    if (tid < DS) sCA[tid] = Alog[tid] * DTC;
    float caLB = 0.f, aLB = 0.f;
    if (tid < DS) {
        caLB = Alog[tid] * DTC;
        aLB  = __expf(caLB * (float)L);
    }

    const int GDX = gridDim.x;
    const int NR  = (NG + GDX - 1) / GDX;
    cooperative_groups::grid_group gg = cooperative_groups::this_grid();

    for (int r = 0; r < NR; ++r) {
        const int  g   = r * GDX + (int)blockIdx.x;
        const bool act = (g < NG);

        if (act) stage_U(U + (size_t)g * L * DIN, sA, tid);
        __syncthreads();                                 // B1: sA ready

        if (act) {
            // ---- GEMM1 + scale by a_s^-t, transpose-store Bu'^T[s][t],
            //      running sum -> chunk aggregate agg[g][s].
            float ssum = 0.f;
            float fmt  = fmt0;
            #pragma unroll
            for (int mt = 0; mt < 8; ++mt) {
                f4v acc = (f4v){0.f, 0.f, 0.f, 0.f};
                #pragma unroll
                for (int ks = 0; ks < 2; ++ks)
                    acc = __builtin_amdgcn_mfma_f32_16x16x32_bf16(
                        ldfrag(sA, 8, mt, ks, q, m), Bf[ks], acc, 0, 0, 0);
                float f0 = fmt, f1 = f0 * ainv, f2 = f1 * ainv, f3 = f2 * ainv;
                float s0 = acc[0] * f0, s1 = acc[1] * f1;
                float s2 = acc[2] * f2, s3 = acc[3] * f3;
                ssum += (s0 + s1) + (s2 + s3);
                *(s4v*)&sT[gidx(16, w, mt * 2 + (q >> 1), m) + (q & 1) * 4] =
                    pack4(s0, s1, s2, s3);
                fmt *= a16i;
            }
            float wsum = ssum;
            wsum += __shfl_xor(wsum, 16, 64);
            wsum += __shfl_xor(wsum, 32, 64);
            if (q == 0)
                agg[(size_t)g * DS + 16 * w + m] = wsum * aPub;
        }
        __threadfence();
        gg.sync();       // publish agg grid-wide; doubles as block barrier (sT ready)

        if (act) {
            // ---- lookback on waves 0-1 (all needed aggs published),
            //      overlapped with tri-GEMM on all waves.
            if (tid < DS) {
                const int depth = (g < LBD) ? g : LBD;
                float c0 = 0.f, wt = 1.f;
                #pragma unroll 8
                for (int k = 0; k < depth; ++k) {
                    c0 = fmaf(wt, agg[(size_t)(g - 1 - k) * DS + tid], c0);
                    wt *= aLB;
                }
                if (depth == g)                          // include a^(Lg) * h0
                    c0 = fmaf(wt, h0[tid], c0);
                sDc[tid] = __expf(caLB) * c0;            // a_s * carry_s
                if (g == NG - 1)                         // h_final
                    hfin[tid] = fmaf(aLB, c0, agg[(size_t)g * DS + tid]);
            }

            // ---- Tri-GEMM: H'^T[s,t] = sum_{tau<=t} Bu'^T[s,tau]
            const int KBmax = w >> 1;
            const int thr   = m + 16 * (w & 1);
            s8v ones, part;
            {
                union { unsigned short u[8]; s8v v; } o, p;
                #pragma unroll
                for (int j = 0; j < 8; ++j) {
                    o.u[j] = 0x3F80;
                    p.u[j] = (q * 8 + j <= thr) ? 0x3F80 : 0;
                }
                ones = o.v; part = p.v;
            }
            f4v accT[2][4];
            #pragma unroll
            for (int grp = 0; grp < 2; ++grp) {
                #pragma unroll
                for (int i = 0; i < 4; ++i) accT[grp][i] = (f4v){0.f, 0.f, 0.f, 0.f};
                for (int kb = 0; kb <= KBmax; ++kb) {
                    s8v bfr = (kb < KBmax) ? ones : part;
                    #pragma unroll
                    for (int msl = 0; msl < 4; ++msl)
                        accT[grp][msl] = __builtin_amdgcn_mfma_f32_16x16x32_bf16(
                            ldfrag(sT, 16, grp * 4 + msl, kb, q, m), bfr,
                            accT[grp][msl], 0, 0, 0);
                }
            }
            __syncthreads();                    // B3: sDc ready; sT reads done

            // ---- tri epilogue: a_s^t * (cumsum + a_s*carry), pack to bf16
            const float tf = (float)(16 * w + m);
            s4v pk[8];
            #pragma unroll
            for (int grp = 0; grp < 2; ++grp) {
                #pragma unroll
                for (int msl = 0; msl < 4; ++msl) {
                    const int ms = grp * 4 + msl;
                    const float4 cav = *(const float4*)&sCA[16 * ms + 4 * q];
                    const float4 dcv = *(const float4*)&sDc[16 * ms + 4 * q];
                    pk[ms] = pack4(
                        __expf(cav.x * tf) * (accT[grp][msl][0] + dcv.x),
                        __expf(cav.y * tf) * (accT[grp][msl][1] + dcv.y),
                        __expf(cav.z * tf) * (accT[grp][msl][2] + dcv.z),
                        __expf(cav.w * tf) * (accT[grp][msl][3] + dcv.w));
                }
            }

            // C/D raw loads (L2-hot after round 0; latency overlapped)
            float4 craw[4][2], draw[2][2];
            #pragma unroll
            for (int ks = 0; ks < 4; ++ks) {
                const float4* p = (const float4*)(C + (16 * mi + m) * DS + ks * 32 + q * 8);
                craw[ks][0] = p[0]; craw[ks][1] = p[1];
            }
            #pragma unroll
            for (int ks = 0; ks < 2; ++ks) {
                const float4* p = (const float4*)(Dm + (16 * mi + m) * DIN + ks * 32 + q * 8);
                draw[ks][0] = p[0]; draw[ks][1] = p[1];
            }

            // H-frag stores (B3 guaranteed all Bu' reads finished)
            #pragma unroll
            for (int ms = 0; ms < 8; ++ms)
                *(s4v*)&sT[gidx(16, w, ms * 2 + (q >> 1), m) + (q & 1) * 4] = pk[ms];
            __syncthreads();                                 // B4

            // ---- GEMM2: (M=i, N=t) tiles
            s8v Cf[4], Df[2];
            #pragma unroll
            for (int ks = 0; ks < 4; ++ks) Cf[ks] = pack8(craw[ks][0], craw[ks][1]);
            #pragma unroll
            for (int ks = 0; ks < 2; ++ks) Df[ks] = pack8(draw[ks][0], draw[ks][1]);

            f4v acc2[4];
            #pragma unroll
            for (int nn = 0; nn < 4; ++nn) {
                const int nt2 = th * 4 + nn;
                f4v a2 = (f4v){0.f, 0.f, 0.f, 0.f};
                #pragma unroll
                for (int ks = 0; ks < 4; ++ks)
                    a2 = __builtin_amdgcn_mfma_f32_16x16x32_bf16(
                        Cf[ks], ldfrag(sT, 16, nt2, ks, q, m), a2, 0, 0, 0);
                #pragma unroll
                for (int ks = 0; ks < 2; ++ks)
                    a2 = __builtin_amdgcn_mfma_f32_16x16x32_bf16(
                        Df[ks], ldfrag(sA, 8, nt2, ks, q, m), a2, 0, 0, 0);
                acc2[nn] = a2;
            }
            __syncthreads();                                 // B5: LDS reads done

            // stage Y in LDS (stride 68), then linear copy-out
            #pragma unroll
            for (int nn = 0; nn < 4; ++nn) {
                const int t = 16 * (th * 4 + nn) + m;
                *(f4v*)&sY[t * 68 + 16 * mi + 4 * q] = acc2[nn];
            }
            __syncthreads();                                 // B6

            float* Yb = Y + (size_t)g * L * DIN;
            #pragma unroll
            for (int k = 0; k < 4; ++k) {
                const int f   = tid + 512 * k;
                const int row = f >> 4;
                const int col = (f & 15) << 2;
                *(float4*)(Yb + row * 64 + col) = *(const float4*)&sY[row * 68 + col];
            }
        }
        __syncthreads();        // B7: sY reads done before next round's sA writes
    }
}

// ---------------------------------------------------------------- launch
extern "C" void kernel_launch(void* const* d_in, const int* in_sizes, int n_in,
                              void* d_out, int out_size, void* d_ws, size_t ws_size,
                              hipStream_t stream)
{
    const float* U    = (const float*)d_in[0];
    const float* Alog = (const float*)d_in[1];
    const float* B    = (const float*)d_in[2];
    const float* C    = (const float*)d_in[3];
    const float* Dm   = (const float*)d_in[4];
    const float* h0   = (const float*)d_in[5];

    float* out  = (float*)d_out;
    float* Yp   = out;                        // T*DIN
    float* hfin = out + (size_t)TT * DIN;     // 128

    float* agg = (float*)d_ws;                // NG*DS (1 MB)

    static int grid_blocks = 0;
    if (grid_blocks == 0) {                   // host-only queries, capture-safe
        int nb = 0;
        if (hipOccupancyMaxActiveBlocksPerMultiprocessor(&nb, ssm_fused, 512, 0)
                != hipSuccess || nb < 1)
            nb = 2;
        int cus = 256;
        hipDeviceProp_t prop;
        int dev = 0;
        if (hipGetDevice(&dev) == hipSuccess &&
            hipGetDeviceProperties(&prop, dev) == hipSuccess &&
            prop.multiProcessorCount > 0)
            cus = prop.multiProcessorCount;
        grid_blocks = nb * cus;
        if (grid_blocks > NG) grid_blocks = NG;
    }

    void* args[] = {(void*)&U, (void*)&Alog, (void*)&B, (void*)&C, (void*)&Dm,
                    (void*)&h0, (void*)&agg, (void*)&Yp, (void*)&hfin};
    hipLaunchCooperativeKernel((void*)ssm_fused, dim3(grid_blocks), dim3(512),
                               args, 0, stream);
}

// Round 5
// 203.937 us; speedup vs baseline: 4.6593x; 4.6593x over previous
//
#include <hip/hip_runtime.h>

// MinimalSSM via MFMA, scan-free: Bu = U@B^T (bf16 MFMA), then
// H[t,s] = a_s^t * ( cumsum_{tau<=t} a_s^{-tau} Bu[tau,s] + a_s*c0_s )
// (cumsum = triangular ones-GEMM on MFMA). Y = H@C^T + U@D^T.
// R5 structure: K1 -> agg + atomic segAgg (SEGL=16), K2 scans 128 segs,
// K3 parallel weighted lookback + tri-GEMM + GEMM2 (87us, verified R7).
// R10: K1 made persistent multi-chunk (CPB=4, grid 512): double-buffered
// LDS + register prefetch -- next chunk's U loads issue during current
// chunk's MFMA/epilogue, one barrier per chunk. (R9 post-mortem: coop
// grid.sync cost ~270us/round -> single-dispatch global-sync family is
// dead; R8 spin-flags hang per G16. R7 verdict: WRITE_SIZE 2.125x is a
// counter artifact; kernels are latency-bound, not BW-bound.)

#define TT   262144
#define DIN  64
#define DS   128
#define DTC  0.01f
#define L    128
#define NG   (TT / L)        // 2048 chunks
#define SEGL 16
#define NSEG (NG / SEGL)     // 128 segments
#define CPB  4               // chunks per K1 block

typedef short  s8v  __attribute__((ext_vector_type(8)));
typedef short  s4v  __attribute__((ext_vector_type(4)));
typedef float  f4v  __attribute__((ext_vector_type(4)));

__device__ __forceinline__ unsigned short f2bf(float f) {
    unsigned u = __float_as_uint(f);
    u += 0x7fffu + ((u >> 16) & 1u);        // round-to-nearest-even
    return (unsigned short)(u >> 16);
}

__device__ __forceinline__ s8v pack8(float4 a, float4 b) {
    union { unsigned short u[8]; s8v v; } r;
    r.u[0] = f2bf(a.x); r.u[1] = f2bf(a.y); r.u[2] = f2bf(a.z); r.u[3] = f2bf(a.w);
    r.u[4] = f2bf(b.x); r.u[5] = f2bf(b.y); r.u[6] = f2bf(b.z); r.u[7] = f2bf(b.w);
    return r.v;
}

__device__ __forceinline__ s4v pack4(float x, float y, float z, float w) {
    union { unsigned short u[4]; s4v v; } r;
    r.u[0] = f2bf(x); r.u[1] = f2bf(y); r.u[2] = f2bf(z); r.u[3] = f2bf(w);
    return r.v;
}

// Fragment-granule LDS layout for bf16 matrix X[row][col], 8-col granules:
// ushort index = ((rtile*NCO + co)*16 + (mf ^ (co&15))) * 8.
__device__ __forceinline__ int gidx(int NCO, int rtile, int co, int mf) {
    return (((rtile * NCO + co) << 4) + (mf ^ (co & 15))) << 3;
}

__device__ __forceinline__ s8v ldfrag(const unsigned short* S, int NCO,
                                      int rtile, int kt, int q, int m) {
    return *(const s8v*)&S[gidx(NCO, rtile, kt * 4 + q, m)];
}

// Stage U chunk (128 x 64 fp32) -> bf16 A-frag granules (fused form).
__device__ __forceinline__ void stage_U(const float* __restrict__ Ug,
                                        unsigned short* __restrict__ sA,
                                        int tid) {
    #pragma unroll
    for (int p = 0; p < 2; ++p) {
        int u  = tid + p * 512;
        int co = u & 7, m = (u >> 3) & 15, mt = u >> 7;
        const float4* gp = (const float4*)(Ug + (mt * 16 + m) * DIN + co * 8);
        *(s8v*)&sA[gidx(8, mt, co, m)] = pack8(gp[0], gp[1]);
    }
}

// Split staging for the K1 pipeline: load to regs / write regs to LDS.
__device__ __forceinline__ void load_U_regs(const float* __restrict__ Ug,
                                            int tid, float4 r[4]) {
    #pragma unroll
    for (int p = 0; p < 2; ++p) {
        int u  = tid + p * 512;
        int co = u & 7, m = (u >> 3) & 15, mt = u >> 7;
        const float4* gp = (const float4*)(Ug + (mt * 16 + m) * DIN + co * 8);
        r[2 * p]     = gp[0];
        r[2 * p + 1] = gp[1];
    }
}

__device__ __forceinline__ void write_U_lds(unsigned short* __restrict__ sA,
                                            int tid, const float4 r[4]) {
    #pragma unroll
    for (int p = 0; p < 2; ++p) {
        int u  = tid + p * 512;
        int co = u & 7, m = (u >> 3) & 15, mt = u >> 7;
        *(s8v*)&sA[gidx(8, mt, co, m)] = pack8(r[2 * p], r[2 * p + 1]);
    }
}

__device__ __forceinline__ s8v load_bfrag(const float* __restrict__ M,
                                          int row, int k0, int ld) {
    const float4* p = (const float4*)(M + row * ld + k0);
    return pack8(p[0], p[1]);
}

// ---------------------------------------------------------------- K1
// agg[g][s] = sum_t a_s^(L-1-t) Bu[t,s]; weighted fold into segAgg (atomic).
// Persistent over CPB chunks with dbuf LDS + reg prefetch: one barrier per
// chunk; next chunk's HBM latency hides under current MFMA/epilogue.
__global__ __launch_bounds__(512, 4) void ssm_k1(
    const float* __restrict__ U, const float* __restrict__ Alog,
    const float* __restrict__ B, float* __restrict__ agg,
    float* __restrict__ segAgg)
{
    __shared__ __align__(16) unsigned short sA[2][8192];   // 2 x 16 KB
    const int g0   = blockIdx.x * CPB;
    const int tid  = threadIdx.x;
    const int lane = tid & 63;
    const int w    = tid >> 6;
    const int q    = lane >> 4, m = lane & 15;
    const int s    = 16 * w + m;

    // hoisted constants
    s8v Bf[2];
    #pragma unroll
    for (int ks = 0; ks < 2; ++ks)
        Bf[ks] = load_bfrag(B, s, ks * 32 + q * 8, DIN);
    const float cA   = Alog[s] * DTC;
    const float ainv = __expf(-cA);
    const float a16i = __expf(-16.f * cA);
    const float wmt0 = __expf(cA * (float)(127 - 4 * q));
    const float aSegStep = __expf(-cA * (float)L);   // step for wgt across chunks
    // wgt(g) = exp(cA * L*(SEGL-1-(g&15))); g0 aligned to CPB, g0&15 = (g0&15)
    float wgt = __expf(cA * (float)(L * (SEGL - 1 - (g0 & (SEGL - 1)))));

    float4 ureg[4];
    load_U_regs(U + (size_t)g0 * L * DIN, tid, ureg);

    for (int c = 0; c < CPB; ++c) {
        const int g = g0 + c;
        unsigned short* sAb = &sA[c & 1][0];
        write_U_lds(sAb, tid, ureg);
        if (c + 1 < CPB)
            load_U_regs(U + (size_t)(g + 1) * L * DIN, tid, ureg);
        __syncthreads();      // sA[c&1] ready; prev buffer's readers all past

        float wmt  = wmt0;
        float wsum = 0.f;
        #pragma unroll
        for (int mt = 0; mt < 8; ++mt) {
            f4v acc = (f4v){0.f, 0.f, 0.f, 0.f};
            #pragma unroll
            for (int ks = 0; ks < 2; ++ks)
                acc = __builtin_amdgcn_mfma_f32_16x16x32_bf16(
                    ldfrag(sAb, 8, mt, ks, q, m), Bf[ks], acc, 0, 0, 0);
            float wr = wmt;
            #pragma unroll
            for (int r = 0; r < 4; ++r) {
                wsum = fmaf(wr, acc[r], wsum);
                wr *= ainv;
            }
            wmt *= a16i;
        }
        wsum += __shfl_xor(wsum, 16, 64);
        wsum += __shfl_xor(wsum, 32, 64);

        if (q == 0) {
            agg[(size_t)g * DS + s] = wsum;
            atomicAdd(&segAgg[(g >> 4) * DS + s], wsum * wgt);
        }
        wgt *= aSegStep;
    }
}

// ---------------------------------------------------------------- K2
// Serial scan over 128 segment aggregates -> segment carries + h_final.
__global__ void ssm_k2(const float* __restrict__ Alog, const float* __restrict__ h0,
                       const float* __restrict__ segAgg, float* __restrict__ segCarry,
                       float* __restrict__ hfin)
{
    const int s = threadIdx.x;                               // 128 threads
    const float aSeg = __expf(Alog[s] * (DTC * L * SEGL));
    float c = h0[s];
    #pragma unroll 8
    for (int sg = 0; sg < NSEG; ++sg) {
        segCarry[sg * DS + s] = c;
        c = fmaf(aSeg, c, segAgg[sg * DS + s]);
    }
    hfin[s] = c;
}

// ---------------------------------------------------------------- K3
__global__ __launch_bounds__(512, 6) void ssm_k3(
    const float* __restrict__ U, const float* __restrict__ Alog,
    const float* __restrict__ B, const float* __restrict__ C,
    const float* __restrict__ Dm, const float* __restrict__ agg,
    const float* __restrict__ segCarry, float* __restrict__ Y)
{
    __shared__ __align__(16) unsigned char smem[49152];      // 48 KB
    unsigned short* sA = (unsigned short*)smem;              // 16 KB U frags
    unsigned short* sT = (unsigned short*)(smem + 16384);    // 32 KB Bu'^T / H^T
    float*          sY = (float*)smem;                       // overlay, 128x68 f32
    __shared__ float sCA[DS];
    __shared__ float sDc[DS];

    const int g    = blockIdx.x;
    const int tid  = threadIdx.x;
    const int lane = tid & 63;
    const int w    = tid >> 6;
    const int q    = lane >> 4, m = lane & 15;

    s8v Bf[2];
    #pragma unroll
    for (int ks = 0; ks < 2; ++ks)
        Bf[ks] = load_bfrag(B, 16 * w + m, ks * 32 + q * 8, DIN);
    const float cA = Alog[16 * w + m] * DTC;

    stage_U(U + (size_t)g * L * DIN, sA, tid);

    // carry via parallel weighted lookback over <=15 L2-hot agg rows
    if (tid < DS) {
        const float ca  = Alog[tid] * DTC;
        sCA[tid] = ca;
        const float caL = ca * (float)L;
        const float aL  = __expf(caL);
        const int   j   = g & (SEGL - 1);
        const int   gb  = g & ~(SEGL - 1);
        float c0 = segCarry[(g >> 4) * DS + tid] * __expf(caL * (float)j);
        float wt = 1.f;
        for (int c = j - 1; c >= 0; --c) {
            c0 = fmaf(wt, agg[(size_t)(gb + c) * DS + tid], c0);
            wt *= aL;
        }
        sDc[tid] = __expf(ca) * c0;             // a_s * carry_s
    }
    __syncthreads();                                     // B1

    // ---- GEMM1 + scale by a_s^-t, transpose-store Bu'^T[s][t]
    {
        float ainv = __expf(-cA);
        float a16i = __expf(-16.f * cA);
        float fmt  = __expf(-cA * (float)(4 * q));
        #pragma unroll
        for (int mt = 0; mt < 8; ++mt) {
            f4v acc = (f4v){0.f, 0.f, 0.f, 0.f};
            #pragma unroll
            for (int ks = 0; ks < 2; ++ks)
                acc = __builtin_amdgcn_mfma_f32_16x16x32_bf16(
                    ldfrag(sA, 8, mt, ks, q, m), Bf[ks], acc, 0, 0, 0);
            float f0 = fmt, f1 = f0 * ainv, f2 = f1 * ainv, f3 = f2 * ainv;
            s4v pk = pack4(acc[0] * f0, acc[1] * f1, acc[2] * f2, acc[3] * f3);
            *(s4v*)&sT[gidx(16, w, mt * 2 + (q >> 1), m) + (q & 1) * 4] = pk;
            fmt *= a16i;
        }
    }
    __syncthreads();                                     // B2

    // ---- Tri-GEMM: H'^T[s,t] = sum_{tau<=t} Bu'^T[s,tau]
    const int KBmax = w >> 1;
    const int thr   = m + 16 * (w & 1);
    s8v ones, part;
    {
        union { unsigned short u[8]; s8v v; } o, p;
        #pragma unroll
        for (int j = 0; j < 8; ++j) {
            o.u[j] = 0x3F80;
            p.u[j] = (q * 8 + j <= thr) ? 0x3F80 : 0;
        }
        ones = o.v; part = p.v;
    }
    const float tf = (float)(16 * w + m);
    s4v pk[8];
    #pragma unroll
    for (int grp = 0; grp < 2; ++grp) {
        f4v acc[4];
        #pragma unroll
        for (int i = 0; i < 4; ++i) acc[i] = (f4v){0.f, 0.f, 0.f, 0.f};
        for (int kb = 0; kb <= KBmax; ++kb) {
            s8v bfr = (kb < KBmax) ? ones : part;
            #pragma unroll
            for (int msl = 0; msl < 4; ++msl)
                acc[msl] = __builtin_amdgcn_mfma_f32_16x16x32_bf16(
                    ldfrag(sT, 16, grp * 4 + msl, kb, q, m), bfr, acc[msl], 0, 0, 0);
        }
        #pragma unroll
        for (int msl = 0; msl < 4; ++msl) {
            const int ms = grp * 4 + msl;
            const float4 cav = *(const float4*)&sCA[16 * ms + 4 * q];
            const float4 dcv = *(const float4*)&sDc[16 * ms + 4 * q];
            pk[grp * 4 + msl] = pack4(
                __expf(cav.x * tf) * (acc[msl][0] + dcv.x),
                __expf(cav.y * tf) * (acc[msl][1] + dcv.y),
                __expf(cav.z * tf) * (acc[msl][2] + dcv.z),
                __expf(cav.w * tf) * (acc[msl][3] + dcv.w));
        }
    }

    // C/D raw loads (latency overlapped with barriers + sT writes)
    const int mi = w & 3, th = w >> 2;
    float4 craw[4][2], draw[2][2];
    #pragma unroll
    for (int ks = 0; ks < 4; ++ks) {
        const float4* p = (const float4*)(C + (16 * mi + m) * DS + ks * 32 + q * 8);
        craw[ks][0] = p[0]; craw[ks][1] = p[1];
    }
    #pragma unroll
    for (int ks = 0; ks < 2; ++ks) {
        const float4* p = (const float4*)(Dm + (16 * mi + m) * DIN + ks * 32 + q * 8);
        draw[ks][0] = p[0]; draw[ks][1] = p[1];
    }

    __syncthreads();                                     // B3
    #pragma unroll
    for (int ms = 0; ms < 8; ++ms)
        *(s4v*)&sT[gidx(16, w, ms * 2 + (q >> 1), m) + (q & 1) * 4] = pk[ms];
    __syncthreads();                                     // B4

    // ---- GEMM2: (M=i, N=t) tiles; accs held in regs until B5
    s8v Cf[4], Df[2];
    #pragma unroll
    for (int ks = 0; ks < 4; ++ks) Cf[ks] = pack8(craw[ks][0], craw[ks][1]);
    #pragma unroll
    for (int ks = 0; ks < 2; ++ks) Df[ks] = pack8(draw[ks][0], draw[ks][1]);

    f4v acc2[4];
    #pragma unroll
    for (int nn = 0; nn < 4; ++nn) {
        const int nt2 = th * 4 + nn;
        f4v a2 = (f4v){0.f, 0.f, 0.f, 0.f};
        #pragma unroll
        for (int ks = 0; ks < 4; ++ks)
            a2 = __builtin_amdgcn_mfma_f32_16x16x32_bf16(
                Cf[ks], ldfrag(sT, 16, nt2, ks, q, m), a2, 0, 0, 0);
        #pragma unroll
        for (int ks = 0; ks < 2; ++ks)
            a2 = __builtin_amdgcn_mfma_f32_16x16x32_bf16(
                Df[ks], ldfrag(sA, 8, nt2, ks, q, m), a2, 0, 0, 0);
        acc2[nn] = a2;
    }
    __syncthreads();                                     // B5: all LDS reads done

    // stage Y in LDS (stride 68: <=2-way banks), then linear copy-out
    #pragma unroll
    for (int nn = 0; nn < 4; ++nn) {
        const int t = 16 * (th * 4 + nn) + m;
        *(f4v*)&sY[t * 68 + 16 * mi + 4 * q] = acc2[nn];
    }
    __syncthreads();                                     // B6

    // Linear mapping: float4 index f = tid + 512k -> byte addr = Yb*4 + 16f.
    float* Yb = Y + (size_t)g * L * DIN;
    #pragma unroll
    for (int k = 0; k < 4; ++k) {
        const int f   = tid + 512 * k;
        const int row = f >> 4;
        const int col = (f & 15) << 2;
        *(float4*)(Yb + row * 64 + col) = *(const float4*)&sY[row * 68 + col];
    }
}

// ---------------------------------------------------------------- launch
extern "C" void kernel_launch(void* const* d_in, const int* in_sizes, int n_in,
                              void* d_out, int out_size, void* d_ws, size_t ws_size,
                              hipStream_t stream)
{
    const float* U    = (const float*)d_in[0];
    const float* Alog = (const float*)d_in[1];
    const float* B    = (const float*)d_in[2];
    const float* C    = (const float*)d_in[3];
    const float* Dm   = (const float*)d_in[4];
    const float* h0   = (const float*)d_in[5];

    float* out  = (float*)d_out;
    float* Yp   = out;                        // T*DIN
    float* hfin = out + (size_t)TT * DIN;     // 128

    float* agg      = (float*)d_ws;                 // NG*DS    (1 MB)
    float* segAgg   = agg + (size_t)NG * DS;        // NSEG*DS  (64 KB)
    float* segCarry = segAgg + (size_t)NSEG * DS;   // NSEG*DS  (64 KB)

    hipMemsetAsync(segAgg, 0, (size_t)NSEG * DS * sizeof(float), stream);
    ssm_k1<<<NG / CPB, 512, 0, stream>>>(U, Alog, B, agg, segAgg);
    ssm_k2<<<1, DS, 0, stream>>>(Alog, h0, segAgg, segCarry, hfin);
    ssm_k3<<<NG, 512, 0, stream>>>(U, Alog, B, C, Dm, agg, segCarry, Yp);
}

// Round 6
// 190.973 us; speedup vs baseline: 4.9756x; 1.0679x over previous
//
#include <hip/hip_runtime.h>

// MinimalSSM via MFMA, scan-free: Bu = U@B^T (bf16 MFMA), then
// H[t,s] = a_s^t * ( cumsum_{tau<=t} a_s^{-tau} Bu[tau,s] + a_s*c0_s )
// (cumsum = triangular ones-GEMM on MFMA). Y = H@C^T + U@D^T.
// R11: (a) f2bf bit-twiddle (5 VALU ops/elem) -> hardware __bf16 cast
//      (m240: scalar cast lowers well on gfx950). ~500 VALU ops/thread
//      cut in K3, ~80 in K1.
//      (b) K2 DELETED: a^(16L) <= 3e-7 even at 5sigma, so K3 rebuilds the
//      segment carry from a depth-2 truncated lookback over segAgg
//      (error <= 3e-6). h0 enters with weight exp(caL*g); h_final from
//      the last K3 block (aL*c0 + agg[NG-1]).
//      (c) K1 back to grid-2048 single-chunk, launch_bounds(512) with NO
//      forced min-waves (removes the (512,8) 64-VGPR spill suspect).
// Accounting (R9 calibration: fixed overhead ~30us): K1 ~80us remains the
// unexplained elephant; with K3 dropping below it, K1 surfaces in top-5
// next round for direct measurement.
// (R7 verdict: WRITE_SIZE ~2.1x is a counter artifact. R8 spin hangs per
// G16; R9 coop grid.sync ~270us/round -> both fusion families dead.)

#define TT   262144
#define DIN  64
#define DS   128
#define DTC  0.01f
#define L    128
#define NG   (TT / L)        // 2048 chunks
#define SEGL 16
#define NSEG (NG / SEGL)     // 128 segments

typedef short  s8v  __attribute__((ext_vector_type(8)));
typedef short  s4v  __attribute__((ext_vector_type(4)));
typedef float  f4v  __attribute__((ext_vector_type(4)));

__device__ __forceinline__ unsigned short f2bf(float f) {
    union { __bf16 h; unsigned short u; } cv;
    cv.h = (__bf16)f;                       // hw cvt on gfx950, RNE
    return cv.u;
}

__device__ __forceinline__ s8v pack8(float4 a, float4 b) {
    union { unsigned short u[8]; s8v v; } r;
    r.u[0] = f2bf(a.x); r.u[1] = f2bf(a.y); r.u[2] = f2bf(a.z); r.u[3] = f2bf(a.w);
    r.u[4] = f2bf(b.x); r.u[5] = f2bf(b.y); r.u[6] = f2bf(b.z); r.u[7] = f2bf(b.w);
    return r.v;
}

__device__ __forceinline__ s4v pack4(float x, float y, float z, float w) {
    union { unsigned short u[4]; s4v v; } r;
    r.u[0] = f2bf(x); r.u[1] = f2bf(y); r.u[2] = f2bf(z); r.u[3] = f2bf(w);
    return r.v;
}

// Fragment-granule LDS layout for bf16 matrix X[row][col], 8-col granules:
// ushort index = ((rtile*NCO + co)*16 + (mf ^ (co&15))) * 8.
__device__ __forceinline__ int gidx(int NCO, int rtile, int co, int mf) {
    return (((rtile * NCO + co) << 4) + (mf ^ (co & 15))) << 3;
}

__device__ __forceinline__ s8v ldfrag(const unsigned short* S, int NCO,
                                      int rtile, int kt, int q, int m) {
    return *(const s8v*)&S[gidx(NCO, rtile, kt * 4 + q, m)];
}

// Stage U chunk (128 x 64 fp32) -> bf16 A-frag granules.
__device__ __forceinline__ void stage_U(const float* __restrict__ Ug,
                                        unsigned short* __restrict__ sA,
                                        int tid) {
    #pragma unroll
    for (int p = 0; p < 2; ++p) {
        int u  = tid + p * 512;
        int co = u & 7, m = (u >> 3) & 15, mt = u >> 7;
        const float4* gp = (const float4*)(Ug + (mt * 16 + m) * DIN + co * 8);
        *(s8v*)&sA[gidx(8, mt, co, m)] = pack8(gp[0], gp[1]);
    }
}

__device__ __forceinline__ s8v load_bfrag(const float* __restrict__ M,
                                          int row, int k0, int ld) {
    const float4* p = (const float4*)(M + row * ld + k0);
    return pack8(p[0], p[1]);
}

// ---------------------------------------------------------------- K1
// agg[g][s] = sum_t a_s^(L-1-t) Bu[t,s]; weighted fold into segAgg (atomic).
__global__ __launch_bounds__(512) void ssm_k1(
    const float* __restrict__ U, const float* __restrict__ Alog,
    const float* __restrict__ B, float* __restrict__ agg,
    float* __restrict__ segAgg)
{
    __shared__ __align__(16) unsigned short sA[8192];   // 16 KB
    const int g    = blockIdx.x;
    const int tid  = threadIdx.x;
    const int lane = tid & 63;
    const int w    = tid >> 6;
    const int q    = lane >> 4, m = lane & 15;
    const int s    = 16 * w + m;

    stage_U(U + (size_t)g * L * DIN, sA, tid);

    s8v Bf[2];
    #pragma unroll
    for (int ks = 0; ks < 2; ++ks)
        Bf[ks] = load_bfrag(B, s, ks * 32 + q * 8, DIN);

    const float cA = Alog[s] * DTC;
    __syncthreads();

    float ainv = __expf(-cA);
    float a16i = __expf(-16.f * cA);
    float wmt  = __expf(cA * (float)(127 - 4 * q));
    float wsum = 0.f;
    #pragma unroll
    for (int mt = 0; mt < 8; ++mt) {
        f4v acc = (f4v){0.f, 0.f, 0.f, 0.f};
        #pragma unroll
        for (int ks = 0; ks < 2; ++ks)
            acc = __builtin_amdgcn_mfma_f32_16x16x32_bf16(
                ldfrag(sA, 8, mt, ks, q, m), Bf[ks], acc, 0, 0, 0);
        float wr = wmt;
        #pragma unroll
        for (int r = 0; r < 4; ++r) {
            wsum = fmaf(wr, acc[r], wsum);
            wr *= ainv;
        }
        wmt *= a16i;
    }
    wsum += __shfl_xor(wsum, 16, 64);
    wsum += __shfl_xor(wsum, 32, 64);

    if (q == 0) {
        agg[(size_t)g * DS + s] = wsum;
        float wgt = __expf(cA * (float)(L * (SEGL - 1 - (g & (SEGL - 1)))));
        atomicAdd(&segAgg[(g >> 4) * DS + s], wsum * wgt);
    }
}

// ---------------------------------------------------------------- K3
__global__ __launch_bounds__(512, 6) void ssm_k3(
    const float* __restrict__ U, const float* __restrict__ Alog,
    const float* __restrict__ B, const float* __restrict__ C,
    const float* __restrict__ Dm, const float* __restrict__ h0,
    const float* __restrict__ agg, const float* __restrict__ segAgg,
    float* __restrict__ Y, float* __restrict__ hfin)
{
    __shared__ __align__(16) unsigned char smem[49152];      // 48 KB
    unsigned short* sA = (unsigned short*)smem;              // 16 KB U frags
    unsigned short* sT = (unsigned short*)(smem + 16384);    // 32 KB Bu'^T / H^T
    float*          sY = (float*)smem;                       // overlay, 128x68 f32
    __shared__ float sCA[DS];
    __shared__ float sDc[DS];

    const int g    = blockIdx.x;
    const int tid  = threadIdx.x;
    const int lane = tid & 63;
    const int w    = tid >> 6;
    const int q    = lane >> 4, m = lane & 15;

    s8v Bf[2];
    #pragma unroll
    for (int ks = 0; ks < 2; ++ks)
        Bf[ks] = load_bfrag(B, 16 * w + m, ks * 32 + q * 8, DIN);
    const float cA = Alog[16 * w + m] * DTC;

    stage_U(U + (size_t)g * L * DIN, sA, tid);

    // carry: depth-2 truncated segment lookback over segAgg (a^(16L) <=
    // 3e-7 worst-case -> dropped depth>=3 terms < 1e-12 rel), then exact
    // within-segment lookback over <=15 L2-hot agg rows, then h0 term.
    if (tid < DS) {
        const float ca  = Alog[tid] * DTC;
        sCA[tid] = ca;
        const float caL = ca * (float)L;
        const float aL  = __expf(caL);
        const int   j   = g & (SEGL - 1);
        const int   gb  = g & ~(SEGL - 1);
        const int   sg  = g >> 4;
        float sc = 0.f;
        if (sg >= 1) sc = segAgg[(sg - 1) * DS + tid];
        if (sg >= 2) sc = fmaf(__expf(caL * 16.f), segAgg[(sg - 2) * DS + tid], sc);
        float c0 = sc * __expf(caL * (float)j);
        float wt = 1.f;
        for (int c = j - 1; c >= 0; --c) {
            c0 = fmaf(wt, agg[(size_t)(gb + c) * DS + tid], c0);
            wt *= aL;
        }
        c0 = fmaf(__expf(caL * (float)g), h0[tid], c0);  // underflows to 0 for large g
        sDc[tid] = __expf(ca) * c0;             // a_s * carry_s
        if (g == NG - 1)                        // h_final = aL*c0 + agg[NG-1]
            hfin[tid] = fmaf(aL, c0, agg[(size_t)g * DS + tid]);
    }
    __syncthreads();                                     // B1

    // ---- GEMM1 + scale by a_s^-t, transpose-store Bu'^T[s][t]
    {
        float ainv = __expf(-cA);
        float a16i = __expf(-16.f * cA);
        float fmt  = __expf(-cA * (float)(4 * q));
        #pragma unroll
        for (int mt = 0; mt < 8; ++mt) {
            f4v acc = (f4v){0.f, 0.f, 0.f, 0.f};
            #pragma unroll
            for (int ks = 0; ks < 2; ++ks)
                acc = __builtin_amdgcn_mfma_f32_16x16x32_bf16(
                    ldfrag(sA, 8, mt, ks, q, m), Bf[ks], acc, 0, 0, 0);
            float f0 = fmt, f1 = f0 * ainv, f2 = f1 * ainv, f3 = f2 * ainv;
            s4v pk = pack4(acc[0] * f0, acc[1] * f1, acc[2] * f2, acc[3] * f3);
            *(s4v*)&sT[gidx(16, w, mt * 2 + (q >> 1), m) + (q & 1) * 4] = pk;
            fmt *= a16i;
        }
    }
    __syncthreads();                                     // B2

    // ---- Tri-GEMM: H'^T[s,t] = sum_{tau<=t} Bu'^T[s,tau]
    const int KBmax = w >> 1;
    const int thr   = m + 16 * (w & 1);
    s8v ones, part;
    {
        union { unsigned short u[8]; s8v v; } o, p;
        #pragma unroll
        for (int j = 0; j < 8; ++j) {
            o.u[j] = 0x3F80;
            p.u[j] = (q * 8 + j <= thr) ? 0x3F80 : 0;
        }
        ones = o.v; part = p.v;
    }
    const float tf = (float)(16 * w + m);
    s4v pk[8];
    #pragma unroll
    for (int grp = 0; grp < 2; ++grp) {
        f4v acc[4];
        #pragma unroll
        for (int i = 0; i < 4; ++i) acc[i] = (f4v){0.f, 0.f, 0.f, 0.f};
        for (int kb = 0; kb <= KBmax; ++kb) {
            s8v bfr = (kb < KBmax) ? ones : part;
            #pragma unroll
            for (int msl = 0; msl < 4; ++msl)
                acc[msl] = __builtin_amdgcn_mfma_f32_16x16x32_bf16(
                    ldfrag(sT, 16, grp * 4 + msl, kb, q, m), bfr, acc[msl], 0, 0, 0);
        }
        #pragma unroll
        for (int msl = 0; msl < 4; ++msl) {
            const int ms = grp * 4 + msl;
            const float4 cav = *(const float4*)&sCA[16 * ms + 4 * q];
            const float4 dcv = *(const float4*)&sDc[16 * ms + 4 * q];
            pk[grp * 4 + msl] = pack4(
                __expf(cav.x * tf) * (acc[msl][0] + dcv.x),
                __expf(cav.y * tf) * (acc[msl][1] + dcv.y),
                __expf(cav.z * tf) * (acc[msl][2] + dcv.z),
                __expf(cav.w * tf) * (acc[msl][3] + dcv.w));
        }
    }

    // C/D raw loads (latency overlapped with barriers + sT writes)
    const int mi = w & 3, th = w >> 2;
    float4 craw[4][2], draw[2][2];
    #pragma unroll
    for (int ks = 0; ks < 4; ++ks) {
        const float4* p = (const float4*)(C + (16 * mi + m) * DS + ks * 32 + q * 8);
        craw[ks][0] = p[0]; craw[ks][1] = p[1];
    }
    #pragma unroll
    for (int ks = 0; ks < 2; ++ks) {
        const float4* p = (const float4*)(Dm + (16 * mi + m) * DIN + ks * 32 + q * 8);
        draw[ks][0] = p[0]; draw[ks][1] = p[1];
    }

    __syncthreads();                                     // B3
    #pragma unroll
    for (int ms = 0; ms < 8; ++ms)
        *(s4v*)&sT[gidx(16, w, ms * 2 + (q >> 1), m) + (q & 1) * 4] = pk[ms];
    __syncthreads();                                     // B4

    // ---- GEMM2: (M=i, N=t) tiles; accs held in regs until B5
    s8v Cf[4], Df[2];
    #pragma unroll
    for (int ks = 0; ks < 4; ++ks) Cf[ks] = pack8(craw[ks][0], craw[ks][1]);
    #pragma unroll
    for (int ks = 0; ks < 2; ++ks) Df[ks] = pack8(draw[ks][0], draw[ks][1]);

    f4v acc2[4];
    #pragma unroll
    for (int nn = 0; nn < 4; ++nn) {
        const int nt2 = th * 4 + nn;
        f4v a2 = (f4v){0.f, 0.f, 0.f, 0.f};
        #pragma unroll
        for (int ks = 0; ks < 4; ++ks)
            a2 = __builtin_amdgcn_mfma_f32_16x16x32_bf16(
                Cf[ks], ldfrag(sT, 16, nt2, ks, q, m), a2, 0, 0, 0);
        #pragma unroll
        for (int ks = 0; ks < 2; ++ks)
            a2 = __builtin_amdgcn_mfma_f32_16x16x32_bf16(
                Df[ks], ldfrag(sA, 8, nt2, ks, q, m), a2, 0, 0, 0);
        acc2[nn] = a2;
    }
    __syncthreads();                                     // B5: all LDS reads done

    // stage Y in LDS (stride 68: <=2-way banks), then linear copy-out
    #pragma unroll
    for (int nn = 0; nn < 4; ++nn) {
        const int t = 16 * (th * 4 + nn) + m;
        *(f4v*)&sY[t * 68 + 16 * mi + 4 * q] = acc2[nn];
    }
    __syncthreads();                                     // B6

    // Linear mapping: float4 index f = tid + 512k -> byte addr = Yb*4 + 16f.
    float* Yb = Y + (size_t)g * L * DIN;
    #pragma unroll
    for (int k = 0; k < 4; ++k) {
        const int f   = tid + 512 * k;
        const int row = f >> 4;
        const int col = (f & 15) << 2;
        *(float4*)(Yb + row * 64 + col) = *(const float4*)&sY[row * 68 + col];
    }
}

// ---------------------------------------------------------------- launch
extern "C" void kernel_launch(void* const* d_in, const int* in_sizes, int n_in,
                              void* d_out, int out_size, void* d_ws, size_t ws_size,
                              hipStream_t stream)
{
    const float* U    = (const float*)d_in[0];
    const float* Alog = (const float*)d_in[1];
    const float* B    = (const float*)d_in[2];
    const float* C    = (const float*)d_in[3];
    const float* Dm   = (const float*)d_in[4];
    const float* h0   = (const float*)d_in[5];

    float* out  = (float*)d_out;
    float* Yp   = out;                        // T*DIN
    float* hfin = out + (size_t)TT * DIN;     // 128

    float* agg    = (float*)d_ws;                 // NG*DS    (1 MB)
    float* segAgg = agg + (size_t)NG * DS;        // NSEG*DS  (64 KB)

    hipMemsetAsync(segAgg, 0, (size_t)NSEG * DS * sizeof(float), stream);
    ssm_k1<<<NG, 512, 0, stream>>>(U, Alog, B, agg, segAgg);
    ssm_k3<<<NG, 512, 0, stream>>>(U, Alog, B, C, Dm, h0, agg, segAgg, Yp, hfin);
}